// Round 6
// baseline (290.035 us; speedup 1.0000x reference)
//
#include <hip/hip_runtime.h>

// Problem constants (fixed-shape problem)
#define BB 4
#define CC 16
#define KK 16
#define HWP (512 * 512)
#define TPB 1024                  // pixels per block (4 waves x 256)
#define TPW 256                   // pixels per wave (8 MFMA groups of 32)
#define NTILES (HWP / TPB)        // 256 tiles per batch -> 1024 blocks
#define NBLOCKS (BB * NTILES)     // 1024
#define THREADS 256
#define NGROUP (TPW / 32)         // 8
#define NSLICE 16                 // atomic contention slices
#define WSTOT (64 + 1024 + 1024)  // floats per slice: cnt | sum | sq
#define CNT_IDX (NSLICE * WSTOT)  // done-counter slot (u32) after the slices

typedef short bf16x8 __attribute__((ext_vector_type(8)));   // 8 bf16 (4 VGPRs)
typedef float f32x4 __attribute__((ext_vector_type(4)));    // MFMA C/D

__device__ __forceinline__ float fmaxf_(float a, float b) { return a > b ? a : b; }

// fp32 -> bf16 round-to-nearest-even (bit trick; no NaN in this data)
__device__ __forceinline__ unsigned short f2bf(float f) {
    unsigned u = __float_as_uint(f);
    u += 0x7FFFu + ((u >> 16) & 1u);
    return (unsigned short)(u >> 16);
}
__device__ __forceinline__ unsigned pkbf(float x, float y) {
    return (unsigned)f2bf(x) | ((unsigned)f2bf(y) << 16);
}

// Round-15: dispatch-boundary play.
// Rounds 0-5 matrix: occupancy 17-55%, in-flight 8->96 KB/CU, stream count
// and run length 4x — ALL null; mfma kernel pinned at ~43us (3.1 TB/s
// blended). Meanwhile total-minus-kernel-time ~95us has been invariant.
// This round: fuse finalize into the main kernel (last-block pattern),
// removing one 2048-block->1-block dispatch boundary + its drain.
// Compute body = round-0 kernel verbatim (proven best, smallest LDS).
// Sync pattern (G16-sound): all ws writes are device-scope atomics
// (coherent point); per-thread __threadfence drains them; counter atomic
// is the release/acquire pivot; reader fences before re-reading ws.
__global__ __launch_bounds__(THREADS) void disc_fused_kernel(
    const float* __restrict__ emb, const int* __restrict__ masks,
    float* __restrict__ ws,   // NSLICE x [cnt 64 | sum 1024 | sq 1024] + counter
    float* __restrict__ out)
{
    __shared__ __align__(16) unsigned short bits[TPB];  // 2 KB, per-wave regions
    __shared__ float redbuf[4][64][9];   // pad 8->9: conflict-light reduce
    __shared__ float cnt_red[4][16];
    __shared__ int islast;

    const int tid = threadIdx.x;
    const int lane = tid & 63;
    const int wave = tid >> 6;
    const int b = blockIdx.x / NTILES;
    const int tile = blockIdx.x % NTILES;
    const size_t base_px = (size_t)tile * TPB + wave * TPW;

    const int quad = lane >> 4;     // 0..3
    const int r = lane & 15;        // A-row (mask idx) == B-col (channel idx)

    // ---- phase 1: pack this wave's 256 px of mask bits (int4: 4 px/lane) ----
    const int* mbase = masks + (size_t)b * KK * HWP + base_px + 4 * lane;
    unsigned v0 = 0, v1 = 0, v2 = 0, v3 = 0;
    #pragma unroll
    for (int k = 0; k < KK; ++k) {
        int4 mm = *(const int4*)(mbase + (size_t)k * HWP);
        v0 |= (mm.x > 0 ? 1u : 0u) << k;
        v1 |= (mm.y > 0 ? 1u : 0u) << k;
        v2 |= (mm.z > 0 ? 1u : 0u) << k;
        v3 |= (mm.w > 0 ? 1u : 0u) << k;
    }
    uint2 pk;
    pk.x = v0 | (v1 << 16);
    pk.y = v2 | (v3 << 16);
    ((uint2*)bits)[(wave * TPW) / 4 + lane] = pk;   // pixels base+4*lane..+3
    // no barrier: this wave reads only bits[wave*TPW .. +255], written above
    // by its own lanes (DS ops wave-ordered; compiler emits the lgkmcnt wait)

    // ---- phase 2: 8 groups of 32 px; 3 MFMAs each ----
    union { bf16x8 v; unsigned short s[8]; } Bones;
    #pragma unroll
    for (int i = 0; i < 8; ++i) Bones.s[i] = 0x3F80;   // bf16 1.0

    const float* ebase = emb + ((size_t)b * CC + r) * HWP + base_px;  // channel r

    f32x4 acc_s = {0.f, 0.f, 0.f, 0.f};
    f32x4 acc_q = {0.f, 0.f, 0.f, 0.f};
    f32x4 acc_c = {0.f, 0.f, 0.f, 0.f};

    #pragma unroll
    for (int g = 0; g < NGROUP; ++g) {
        const int p0 = wave * TPW + g * 32;

        // A-frag: mask bit r of pixels p0+quad*8..+7 (16B LDS read, 4-lane bcast)
        uint4 bw = *(const uint4*)&bits[p0 + quad * 8];
        union { bf16x8 v; unsigned u[4]; } A;
        A.u[0] = ((bw.x >> r) & 0x00010001u) * 0x3F80u;
        A.u[1] = ((bw.y >> r) & 0x00010001u) * 0x3F80u;
        A.u[2] = ((bw.z >> r) & 0x00010001u) * 0x3F80u;
        A.u[3] = ((bw.w >> r) & 0x00010001u) * 0x3F80u;

        // B-frags: channel r, pixels g*32+quad*8..+7 (two float4 loads)
        const float4* ep = (const float4*)(ebase + g * 32 + quad * 8);
        float4 f0 = ep[0], f1 = ep[1];
        union { bf16x8 v; unsigned u[4]; } Bf, B2;
        Bf.u[0] = pkbf(f0.x, f0.y);
        Bf.u[1] = pkbf(f0.z, f0.w);
        Bf.u[2] = pkbf(f1.x, f1.y);
        Bf.u[3] = pkbf(f1.z, f1.w);
        B2.u[0] = pkbf(f0.x * f0.x, f0.y * f0.y);
        B2.u[1] = pkbf(f0.z * f0.z, f0.w * f0.w);
        B2.u[2] = pkbf(f1.x * f1.x, f1.y * f1.y);
        B2.u[3] = pkbf(f1.z * f1.z, f1.w * f1.w);

        acc_s = __builtin_amdgcn_mfma_f32_16x16x32_bf16(A.v, Bf.v, acc_s, 0, 0, 0);
        acc_q = __builtin_amdgcn_mfma_f32_16x16x32_bf16(A.v, B2.v, acc_q, 0, 0, 0);
        acc_c = __builtin_amdgcn_mfma_f32_16x16x32_bf16(A.v, Bones.v, acc_c, 0, 0, 0);
    }

    // ---- block-level reduction (C/D: col=lane&15, row=quad*4+reg) ----
    #pragma unroll
    for (int j = 0; j < 4; ++j) {
        redbuf[wave][lane][j] = acc_s[j];
        redbuf[wave][lane][4 + j] = acc_q[j];
    }
    if (r == 0) {   // count cols identical; col-0 lanes own rows quad*4..+3
        #pragma unroll
        for (int reg = 0; reg < 4; ++reg) cnt_red[wave][quad * 4 + reg] = acc_c[reg];
    }
    __syncthreads();

    float* slice = ws + (size_t)(blockIdx.x & (NSLICE - 1)) * WSTOT;
    #pragma unroll
    for (int t = 0; t < 2; ++t) {
        const int fi = tid + t * THREADS;          // 0..511
        const int l2 = fi >> 3, j = fi & 7;
        float v = redbuf[0][l2][j] + redbuf[1][l2][j]
                + redbuf[2][l2][j] + redbuf[3][l2][j];
        const int reg = j & 3, isq = j >> 2;
        const int krow = (l2 >> 4) * 4 + reg;
        const int ccol = l2 & 15;
        atomicAdd(&slice[64 + isq * 1024 + ((size_t)b * KK + krow) * CC + ccol], v);
    }
    if (tid < KK) {
        float ctot = cnt_red[0][tid] + cnt_red[1][tid] + cnt_red[2][tid] + cnt_red[3][tid];
        atomicAdd(&slice[b * KK + tid], ctot);
    }

    // ---- last-block election (release: fence per thread, then signal) ----
    __threadfence();           // drain this wave's outstanding atomics
    __syncthreads();           // whole block's atomics drained
    if (tid == 0) {
        unsigned prev = atomicAdd((unsigned*)ws + CNT_IDX, 1u);
        islast = (prev == (unsigned)(NBLOCKS - 1)) ? 1 : 0;
    }
    __syncthreads();
    if (!islast) return;

    // ================= last block: fused finalize (256 threads) =============
    __threadfence();           // acquire: no stale ws lines

    __shared__ float red[WSTOT];             // slice-reduced [cnt|sum|sq]
    __shared__ float fmeans[BB][KK][CC];
    __shared__ float fpartial[BB];

    // vectorized slice reduction: 528 float4-columns, 16 slices each
    for (int i4 = tid; i4 < WSTOT / 4; i4 += THREADS) {
        float4 t = {0.f, 0.f, 0.f, 0.f};
        #pragma unroll
        for (int s = 0; s < NSLICE; ++s) {
            float4 v = *(const float4*)(ws + (size_t)s * WSTOT + 4 * i4);
            t.x += v.x; t.y += v.y; t.z += v.z; t.w += v.w;
        }
        *(float4*)(red + 4 * i4) = t;
    }
    __syncthreads();

    const float* red_cnt = red;
    const float* red_sum = red + 64;
    const float* red_sq  = red + 64 + 1024;

    const int fb = tid >> 6;      // one wave per batch (4 waves = 4 batches)
    const int fl = tid & 63;

    const float DELTA_PULL = 0.5f;
    const float DELTA_PUSH = 1.5f;
    const float EPS = 1e-6f;

    float cntk = 0.f;
    bool valid = false;
    float pull_k = 0.f;
    if (fl < KK) {
        int k = fl;
        cntk = red_cnt[fb * KK + k];
        valid = cntk > 0.f;
        float safe = fmaxf_(cntk, 1.f);
        float acc_sq = 0.f, acc_ss = 0.f;
        #pragma unroll
        for (int c = 0; c < CC; ++c) {
            float sv = red_sum[(fb * KK + k) * CC + c];
            fmeans[fb][k][c] = sv / safe;
            acc_sq += red_sq[(fb * KK + k) * CC + c];
            acc_ss += sv * sv;
        }
        if (valid) pull_k = (acc_sq - acc_ss / cntk) / (cntk + EPS);
    }

    unsigned long long bal = __ballot(fl < KK && valid);
    float M = (float)__popcll(bal);

    float ps = pull_k;
    #pragma unroll
    for (int d = 32; d >= 1; d >>= 1) ps += __shfl_xor(ps, d, 64);
    float pull_b = ps / fmaxf_(M, 1.f);

    __syncthreads();

    float push = 0.f;
    for (int t = fl; t < KK * KK; t += 64) {
        int i = t >> 4, j = t & 15;
        if (i < j && ((bal >> i) & 1ull) && ((bal >> j) & 1ull)) {
            float d2 = 1e-12f;
            #pragma unroll
            for (int c = 0; c < CC; ++c) {
                float df = fmeans[fb][i][c] - fmeans[fb][j][c];
                d2 = fmaf(df, df, d2);
            }
            float dist = sqrtf(d2);
            float h = fmaxf_(DELTA_PUSH - dist, 0.f);
            push += h * h;
        }
    }
    #pragma unroll
    for (int d = 32; d >= 1; d >>= 1) push += __shfl_xor(push, d, 64);

    if (fl == 0) {
        float npairs = M * (M - 1.f) * 0.5f;
        float push_b = (M > 1.f) ? push / fmaxf_(npairs, 1.f) : 0.f;
        fpartial[fb] = DELTA_PULL * pull_b + push_b;
    }
    __syncthreads();
    if (tid == 0) {
        out[0] = (fpartial[0] + fpartial[1] + fpartial[2] + fpartial[3]) * 0.25f;
    }
}

extern "C" void kernel_launch(void* const* d_in, const int* in_sizes, int n_in,
                              void* d_out, int out_size, void* d_ws, size_t ws_size,
                              hipStream_t stream) {
    const float* emb = (const float*)d_in[0];
    const int* masks = (const int*)d_in[1];
    float* ws = (float*)d_ws;

    // zero slices + done-counter (graph-replay safe: re-zeroed every iteration)
    hipMemsetAsync(d_ws, 0, (NSLICE * WSTOT + 4) * sizeof(float), stream);

    dim3 grid(NBLOCKS);
    disc_fused_kernel<<<grid, THREADS, 0, stream>>>(emb, masks, ws, (float*)d_out);
}

// Round 7
// 191.671 us; speedup vs baseline: 1.5132x; 1.5132x over previous
//
#include <hip/hip_runtime.h>

// Problem constants (fixed-shape problem)
#define BB 4
#define CC 16
#define KK 16
#define HWP (512 * 512)
#define TPB 1024                  // pixels per block (4 waves x 256)
#define TPW 256                   // pixels per wave (8 MFMA groups of 32)
#define NTILES (HWP / TPB)        // 256 tiles per batch -> 1024 blocks
#define THREADS 256
#define NGROUP (TPW / 32)         // 8
#define NSLICE 16                 // atomic contention slices
#define WSTOT (64 + 1024 + 1024)  // floats per slice: cnt | sum | sq

typedef short bf16x8 __attribute__((ext_vector_type(8)));   // 8 bf16 (4 VGPRs)
typedef float f32x4 __attribute__((ext_vector_type(4)));    // MFMA C/D

__device__ __forceinline__ float fmaxf_(float a, float b) { return a > b ? a : b; }

// fp32 -> bf16 round-to-nearest-even (bit trick; no NaN in this data)
__device__ __forceinline__ unsigned short f2bf(float f) {
    unsigned u = __float_as_uint(f);
    u += 0x7FFFu + ((u >> 16) & 1u);
    return (unsigned short)(u >> 16);
}
__device__ __forceinline__ unsigned pkbf(float x, float y) {
    return (unsigned)f2bf(x) | ((unsigned)f2bf(y) << 16);
}

// Round-16: REVERT round-6 fusion (device-scope threadfence per block
// collapsed L2/L3 service: 350 GB/s, 195us — fences in hot path >> dispatch
// boundary cost). Back to proven two-kernel structure (round-0 main +
// round-2 finalize, absmax 0, ~43+8us).
// PLUS: two diagnostic probe dispatches (separate rocprof rows) to ablate
// the 43-us floor — never measured load-only vs compute cost:
//   probe_pattern: exact main-kernel load sequence, asm-sinked, no writes.
//   probe_linear:  same 128 MiB, block-contiguous coalesced reads.
// Decision table pre-committed in journal; probes removed next round.
__global__ __launch_bounds__(THREADS) void disc_mfma_kernel(
    const float* __restrict__ emb, const int* __restrict__ masks,
    float* __restrict__ ws)   // NSLICE slices of [cnt 64 | sum 1024 | sq 1024]
{
    __shared__ __align__(16) unsigned short bits[TPB];  // 2 KB, per-wave regions
    __shared__ float redbuf[4][64][9];   // pad 8->9: conflict-light reduce
    __shared__ float cnt_red[4][16];

    const int tid = threadIdx.x;
    const int lane = tid & 63;
    const int wave = tid >> 6;
    const int b = blockIdx.x / NTILES;
    const int tile = blockIdx.x % NTILES;
    const size_t base_px = (size_t)tile * TPB + wave * TPW;

    const int quad = lane >> 4;     // 0..3
    const int r = lane & 15;        // A-row (mask idx) == B-col (channel idx)

    // ---- phase 1: pack this wave's 256 px of mask bits (int4: 4 px/lane) ----
    const int* mbase = masks + (size_t)b * KK * HWP + base_px + 4 * lane;
    unsigned v0 = 0, v1 = 0, v2 = 0, v3 = 0;
    #pragma unroll
    for (int k = 0; k < KK; ++k) {
        int4 mm = *(const int4*)(mbase + (size_t)k * HWP);
        v0 |= (mm.x > 0 ? 1u : 0u) << k;
        v1 |= (mm.y > 0 ? 1u : 0u) << k;
        v2 |= (mm.z > 0 ? 1u : 0u) << k;
        v3 |= (mm.w > 0 ? 1u : 0u) << k;
    }
    uint2 pk;
    pk.x = v0 | (v1 << 16);
    pk.y = v2 | (v3 << 16);
    ((uint2*)bits)[(wave * TPW) / 4 + lane] = pk;   // pixels base+4*lane..+3
    // no barrier: this wave reads only bits[wave*TPW .. +255], written above
    // by its own lanes (DS ops wave-ordered; compiler emits the lgkmcnt wait)

    // ---- phase 2: 8 groups of 32 px; 3 MFMAs each ----
    union { bf16x8 v; unsigned short s[8]; } Bones;
    #pragma unroll
    for (int i = 0; i < 8; ++i) Bones.s[i] = 0x3F80;   // bf16 1.0

    const float* ebase = emb + ((size_t)b * CC + r) * HWP + base_px;  // channel r

    f32x4 acc_s = {0.f, 0.f, 0.f, 0.f};
    f32x4 acc_q = {0.f, 0.f, 0.f, 0.f};
    f32x4 acc_c = {0.f, 0.f, 0.f, 0.f};

    #pragma unroll
    for (int g = 0; g < NGROUP; ++g) {
        const int p0 = wave * TPW + g * 32;

        // A-frag: mask bit r of pixels p0+quad*8..+7 (16B LDS read, 4-lane bcast)
        uint4 bw = *(const uint4*)&bits[p0 + quad * 8];
        union { bf16x8 v; unsigned u[4]; } A;
        A.u[0] = ((bw.x >> r) & 0x00010001u) * 0x3F80u;
        A.u[1] = ((bw.y >> r) & 0x00010001u) * 0x3F80u;
        A.u[2] = ((bw.z >> r) & 0x00010001u) * 0x3F80u;
        A.u[3] = ((bw.w >> r) & 0x00010001u) * 0x3F80u;

        // B-frags: channel r, pixels g*32+quad*8..+7 (two float4 loads)
        const float4* ep = (const float4*)(ebase + g * 32 + quad * 8);
        float4 f0 = ep[0], f1 = ep[1];
        union { bf16x8 v; unsigned u[4]; } Bf, B2;
        Bf.u[0] = pkbf(f0.x, f0.y);
        Bf.u[1] = pkbf(f0.z, f0.w);
        Bf.u[2] = pkbf(f1.x, f1.y);
        Bf.u[3] = pkbf(f1.z, f1.w);
        B2.u[0] = pkbf(f0.x * f0.x, f0.y * f0.y);
        B2.u[1] = pkbf(f0.z * f0.z, f0.w * f0.w);
        B2.u[2] = pkbf(f1.x * f1.x, f1.y * f1.y);
        B2.u[3] = pkbf(f1.z * f1.z, f1.w * f1.w);

        acc_s = __builtin_amdgcn_mfma_f32_16x16x32_bf16(A.v, Bf.v, acc_s, 0, 0, 0);
        acc_q = __builtin_amdgcn_mfma_f32_16x16x32_bf16(A.v, B2.v, acc_q, 0, 0, 0);
        acc_c = __builtin_amdgcn_mfma_f32_16x16x32_bf16(A.v, Bones.v, acc_c, 0, 0, 0);
    }

    // ---- block-level reduction (C/D: col=lane&15, row=quad*4+reg) ----
    #pragma unroll
    for (int j = 0; j < 4; ++j) {
        redbuf[wave][lane][j] = acc_s[j];
        redbuf[wave][lane][4 + j] = acc_q[j];
    }
    if (r == 0) {   // count cols identical; col-0 lanes own rows quad*4..+3
        #pragma unroll
        for (int reg = 0; reg < 4; ++reg) cnt_red[wave][quad * 4 + reg] = acc_c[reg];
    }
    __syncthreads();

    float* slice = ws + (size_t)(blockIdx.x & (NSLICE - 1)) * WSTOT;
    #pragma unroll
    for (int t = 0; t < 2; ++t) {
        const int fi = tid + t * THREADS;          // 0..511
        const int l2 = fi >> 3, j = fi & 7;
        float v = redbuf[0][l2][j] + redbuf[1][l2][j]
                + redbuf[2][l2][j] + redbuf[3][l2][j];
        const int reg = j & 3, isq = j >> 2;
        const int krow = (l2 >> 4) * 4 + reg;
        const int ccol = l2 & 15;
        atomicAdd(&slice[64 + isq * 1024 + ((size_t)b * KK + krow) * CC + ccol], v);
    }
    if (tid < KK) {
        float ctot = cnt_red[0][tid] + cnt_red[1][tid] + cnt_red[2][tid] + cnt_red[3][tid];
        atomicAdd(&slice[b * KK + tid], ctot);
    }
}

// ---- diagnostic probe A: exact main-kernel load pattern, no writes ----
__global__ __launch_bounds__(THREADS) void probe_pattern(
    const float* __restrict__ emb, const int* __restrict__ masks)
{
    const int tid = threadIdx.x;
    const int lane = tid & 63;
    const int wave = tid >> 6;
    const int b = blockIdx.x / NTILES;
    const int tile = blockIdx.x % NTILES;
    const size_t base_px = (size_t)tile * TPB + wave * TPW;
    const int quad = lane >> 4;
    const int r = lane & 15;

    const int* mbase = masks + (size_t)b * KK * HWP + base_px + 4 * lane;
    #pragma unroll
    for (int k = 0; k < KK; ++k) {
        int4 mm = *(const int4*)(mbase + (size_t)k * HWP);
        asm volatile("" :: "v"(mm.x), "v"(mm.y), "v"(mm.z), "v"(mm.w));
    }
    const float* ebase = emb + ((size_t)b * CC + r) * HWP + base_px;
    #pragma unroll
    for (int g = 0; g < NGROUP; ++g) {
        const float4* ep = (const float4*)(ebase + g * 32 + quad * 8);
        float4 f0 = ep[0], f1 = ep[1];
        asm volatile("" :: "v"(f0.x), "v"(f0.y), "v"(f0.z), "v"(f0.w));
        asm volatile("" :: "v"(f1.x), "v"(f1.y), "v"(f1.z), "v"(f1.w));
    }
}

// ---- diagnostic probe B: same 128 MiB, block-contiguous coalesced ----
__global__ __launch_bounds__(THREADS) void probe_linear(
    const float* __restrict__ emb, const int* __restrict__ masks)
{
    const int tid = threadIdx.x;
    const size_t base = (size_t)blockIdx.x * 16384;   // 16384 elems per block
    #pragma unroll
    for (int i = 0; i < 16; ++i) {
        const size_t off = base + (size_t)i * 1024 + 4 * tid;
        float4 f = *(const float4*)(emb + off);
        int4 m = *(const int4*)(masks + off);
        asm volatile("" :: "v"(f.x), "v"(f.y), "v"(f.z), "v"(f.w));
        asm volatile("" :: "v"(m.x), "v"(m.y), "v"(m.z), "v"(m.w));
    }
}

__global__ __launch_bounds__(1024) void disc_finalize_kernel(
    const float* __restrict__ ws, float* __restrict__ out)
{
    __shared__ float red[WSTOT];             // slice-reduced [cnt|sum|sq]
    __shared__ float means[BB][KK][CC];
    __shared__ float partial[BB];
    const int tid = threadIdx.x;

    // vectorized slice reduction: 528 float4, 16 independent loads each
    for (int i4 = tid; i4 < WSTOT / 4; i4 += 1024) {
        float4 t = {0.f, 0.f, 0.f, 0.f};
        #pragma unroll
        for (int s = 0; s < NSLICE; ++s) {
            float4 v = *(const float4*)(ws + (size_t)s * WSTOT + 4 * i4);
            t.x += v.x; t.y += v.y; t.z += v.z; t.w += v.w;
        }
        *(float4*)(red + 4 * i4) = t;
    }
    __syncthreads();

    const float* red_cnt = red;
    const float* red_sum = red + 64;
    const float* red_sq  = red + 64 + 1024;

    const int b = tid >> 6;       // one wave per batch (waves 0..3 active)
    const int lane = tid & 63;
    const bool active = tid < 256;

    const float DELTA_PULL = 0.5f;
    const float DELTA_PUSH = 1.5f;
    const float EPS = 1e-6f;

    unsigned long long bal = 0ull;
    float M = 0.f, pull_b = 0.f;

    if (active) {
        float cntk = 0.f;
        bool valid = false;
        float pull_k = 0.f;
        if (lane < KK) {
            int k = lane;
            cntk = red_cnt[b * KK + k];
            valid = cntk > 0.f;
            float safe = fmaxf_(cntk, 1.f);
            float acc_sq = 0.f, acc_ss = 0.f;
            #pragma unroll
            for (int c = 0; c < CC; ++c) {
                float sv = red_sum[(b * KK + k) * CC + c];
                means[b][k][c] = sv / safe;
                acc_sq += red_sq[(b * KK + k) * CC + c];
                acc_ss += sv * sv;
            }
            if (valid) pull_k = (acc_sq - acc_ss / cntk) / (cntk + EPS);
        }

        bal = __ballot(lane < KK && valid);
        M = (float)__popcll(bal);

        float ps = pull_k;
        #pragma unroll
        for (int d = 32; d >= 1; d >>= 1) ps += __shfl_xor(ps, d, 64);
        pull_b = ps / fmaxf_(M, 1.f);
    }

    __syncthreads();

    if (active) {
        float push = 0.f;
        for (int t = lane; t < KK * KK; t += 64) {
            int i = t >> 4, j = t & 15;
            if (i < j && ((bal >> i) & 1ull) && ((bal >> j) & 1ull)) {
                float d2 = 1e-12f;
                #pragma unroll
                for (int c = 0; c < CC; ++c) {
                    float df = means[b][i][c] - means[b][j][c];
                    d2 = fmaf(df, df, d2);
                }
                float dist = sqrtf(d2);
                float h = fmaxf_(DELTA_PUSH - dist, 0.f);
                push += h * h;
            }
        }
        #pragma unroll
        for (int d = 32; d >= 1; d >>= 1) push += __shfl_xor(push, d, 64);

        if (lane == 0) {
            float npairs = M * (M - 1.f) * 0.5f;
            float push_b = (M > 1.f) ? push / fmaxf_(npairs, 1.f) : 0.f;
            partial[b] = DELTA_PULL * pull_b + push_b;
        }
    }
    __syncthreads();
    if (tid == 0) {
        out[0] = (partial[0] + partial[1] + partial[2] + partial[3]) * 0.25f;
    }
}

extern "C" void kernel_launch(void* const* d_in, const int* in_sizes, int n_in,
                              void* d_out, int out_size, void* d_ws, size_t ws_size,
                              hipStream_t stream) {
    const float* emb = (const float*)d_in[0];
    const int* masks = (const int*)d_in[1];
    float* ws = (float*)d_ws;

    hipMemsetAsync(d_ws, 0, NSLICE * WSTOT * sizeof(float), stream);

    dim3 grid(BB * NTILES);
    disc_mfma_kernel<<<grid, THREADS, 0, stream>>>(emb, masks, ws);
    disc_finalize_kernel<<<1, 1024, 0, stream>>>(ws, (float*)d_out);

    // diagnostic probes (separate rocprof rows; removed next round)
    probe_pattern<<<grid, THREADS, 0, stream>>>(emb, masks);
    probe_linear<<<grid, THREADS, 0, stream>>>(emb, masks);
}

// Round 9
// 143.414 us; speedup vs baseline: 2.0224x; 1.3365x over previous
//
#include <hip/hip_runtime.h>

// Problem constants (fixed-shape problem)
#define BB 4
#define CC 16
#define KK 16
#define HWP (512 * 512)
#define TPB 1024                  // pixels per block (4 waves x 256)
#define TPW 256                   // pixels per wave (8 MFMA groups of 32)
#define NTILES (HWP / TPB)        // 256 tiles per batch -> 1024 blocks
#define THREADS 256
#define NGROUP (TPW / 32)         // 8
#define NSLICE 16                 // atomic contention slices
#define WSTOT (64 + 1024 + 1024)  // floats per slice: cnt | sum | sq

typedef short bf16x8 __attribute__((ext_vector_type(8)));   // 8 bf16 (4 VGPRs)
typedef float f32x4 __attribute__((ext_vector_type(4)));    // MFMA C/D
typedef int   i32x4 __attribute__((ext_vector_type(4)));    // NT-loadable int4
typedef float fl4v  __attribute__((ext_vector_type(4)));    // NT-loadable float4

__device__ __forceinline__ float fmaxf_(float a, float b) { return a > b ? a : b; }

// fp32 -> bf16 round-to-nearest-even (bit trick; no NaN in this data)
__device__ __forceinline__ unsigned short f2bf(float f) {
    unsigned u = __float_as_uint(f);
    u += 0x7FFFu + ((u >> 16) & 1u);
    return (unsigned short)(u >> 16);
}
__device__ __forceinline__ unsigned pkbf(float x, float y) {
    return (unsigned)f2bf(x) | ((unsigned)f2bf(y) << 16);
}

// Round-18: round-8 NT play, compile-fixed (__builtin_nontemporal_load
// requires clang ext_vector_type, not HIP_vector_type structs).
// Theory (round-7 probes): load pattern is fine from cache (~19us L3-hot);
// main's 43us == 69MB FETCH at 1.6 TB/s — each pass re-fetches a
// random-scattered ~50% line subset (L3 keeps ~64MB of the cyclic 128MB
// stream): worst case for DRAM row locality. NT loads (no L2/L3 allocate)
// make every pass stream all 134MB DENSELY from HBM. No intra-dispatch
// reuse exists -> bypass costs nothing inside the kernel.
// Pre-committed: win = 24-32us @ 4-6 TB/s; null = ~3 TB/s pattern
// roofline (declare next round); regression >50us = revert.
__global__ __launch_bounds__(THREADS) void disc_mfma_kernel(
    const float* __restrict__ emb, const int* __restrict__ masks,
    float* __restrict__ ws)   // NSLICE slices of [cnt 64 | sum 1024 | sq 1024]
{
    __shared__ __align__(16) unsigned short bits[TPB];  // 2 KB, per-wave regions
    __shared__ float redbuf[4][64][9];   // pad 8->9: conflict-light reduce
    __shared__ float cnt_red[4][16];

    const int tid = threadIdx.x;
    const int lane = tid & 63;
    const int wave = tid >> 6;
    const int b = blockIdx.x / NTILES;
    const int tile = blockIdx.x % NTILES;
    const size_t base_px = (size_t)tile * TPB + wave * TPW;

    const int quad = lane >> 4;     // 0..3
    const int r = lane & 15;        // A-row (mask idx) == B-col (channel idx)

    // ---- phase 1: pack this wave's 256 px of mask bits (int4: 4 px/lane) ----
    const int* mbase = masks + (size_t)b * KK * HWP + base_px + 4 * lane;
    unsigned v0 = 0, v1 = 0, v2 = 0, v3 = 0;
    #pragma unroll
    for (int k = 0; k < KK; ++k) {
        i32x4 mm = __builtin_nontemporal_load((const i32x4*)(mbase + (size_t)k * HWP));
        v0 |= (mm.x > 0 ? 1u : 0u) << k;
        v1 |= (mm.y > 0 ? 1u : 0u) << k;
        v2 |= (mm.z > 0 ? 1u : 0u) << k;
        v3 |= (mm.w > 0 ? 1u : 0u) << k;
    }
    uint2 pk;
    pk.x = v0 | (v1 << 16);
    pk.y = v2 | (v3 << 16);
    ((uint2*)bits)[(wave * TPW) / 4 + lane] = pk;   // pixels base+4*lane..+3
    // no barrier: this wave reads only bits[wave*TPW .. +255], written above
    // by its own lanes (DS ops wave-ordered; compiler emits the lgkmcnt wait)

    // ---- phase 2: 8 groups of 32 px; 3 MFMAs each ----
    union { bf16x8 v; unsigned short s[8]; } Bones;
    #pragma unroll
    for (int i = 0; i < 8; ++i) Bones.s[i] = 0x3F80;   // bf16 1.0

    const float* ebase = emb + ((size_t)b * CC + r) * HWP + base_px;  // channel r

    f32x4 acc_s = {0.f, 0.f, 0.f, 0.f};
    f32x4 acc_q = {0.f, 0.f, 0.f, 0.f};
    f32x4 acc_c = {0.f, 0.f, 0.f, 0.f};

    #pragma unroll
    for (int g = 0; g < NGROUP; ++g) {
        const int p0 = wave * TPW + g * 32;

        // A-frag: mask bit r of pixels p0+quad*8..+7 (16B LDS read, 4-lane bcast)
        uint4 bw = *(const uint4*)&bits[p0 + quad * 8];
        union { bf16x8 v; unsigned u[4]; } A;
        A.u[0] = ((bw.x >> r) & 0x00010001u) * 0x3F80u;
        A.u[1] = ((bw.y >> r) & 0x00010001u) * 0x3F80u;
        A.u[2] = ((bw.z >> r) & 0x00010001u) * 0x3F80u;
        A.u[3] = ((bw.w >> r) & 0x00010001u) * 0x3F80u;

        // B-frags: channel r, pixels g*32+quad*8..+7 (two NT vector loads)
        const fl4v* ep = (const fl4v*)(ebase + g * 32 + quad * 8);
        fl4v f0 = __builtin_nontemporal_load(ep);
        fl4v f1 = __builtin_nontemporal_load(ep + 1);
        union { bf16x8 v; unsigned u[4]; } Bf, B2;
        Bf.u[0] = pkbf(f0.x, f0.y);
        Bf.u[1] = pkbf(f0.z, f0.w);
        Bf.u[2] = pkbf(f1.x, f1.y);
        Bf.u[3] = pkbf(f1.z, f1.w);
        B2.u[0] = pkbf(f0.x * f0.x, f0.y * f0.y);
        B2.u[1] = pkbf(f0.z * f0.z, f0.w * f0.w);
        B2.u[2] = pkbf(f1.x * f1.x, f1.y * f1.y);
        B2.u[3] = pkbf(f1.z * f1.z, f1.w * f1.w);

        acc_s = __builtin_amdgcn_mfma_f32_16x16x32_bf16(A.v, Bf.v, acc_s, 0, 0, 0);
        acc_q = __builtin_amdgcn_mfma_f32_16x16x32_bf16(A.v, B2.v, acc_q, 0, 0, 0);
        acc_c = __builtin_amdgcn_mfma_f32_16x16x32_bf16(A.v, Bones.v, acc_c, 0, 0, 0);
    }

    // ---- block-level reduction (C/D: col=lane&15, row=quad*4+reg) ----
    #pragma unroll
    for (int j = 0; j < 4; ++j) {
        redbuf[wave][lane][j] = acc_s[j];
        redbuf[wave][lane][4 + j] = acc_q[j];
    }
    if (r == 0) {   // count cols identical; col-0 lanes own rows quad*4..+3
        #pragma unroll
        for (int reg = 0; reg < 4; ++reg) cnt_red[wave][quad * 4 + reg] = acc_c[reg];
    }
    __syncthreads();

    float* slice = ws + (size_t)(blockIdx.x & (NSLICE - 1)) * WSTOT;
    #pragma unroll
    for (int t = 0; t < 2; ++t) {
        const int fi = tid + t * THREADS;          // 0..511
        const int l2 = fi >> 3, j = fi & 7;
        float v = redbuf[0][l2][j] + redbuf[1][l2][j]
                + redbuf[2][l2][j] + redbuf[3][l2][j];
        const int reg = j & 3, isq = j >> 2;
        const int krow = (l2 >> 4) * 4 + reg;
        const int ccol = l2 & 15;
        atomicAdd(&slice[64 + isq * 1024 + ((size_t)b * KK + krow) * CC + ccol], v);
    }
    if (tid < KK) {
        float ctot = cnt_red[0][tid] + cnt_red[1][tid] + cnt_red[2][tid] + cnt_red[3][tid];
        atomicAdd(&slice[b * KK + tid], ctot);
    }
}

__global__ __launch_bounds__(1024) void disc_finalize_kernel(
    const float* __restrict__ ws, float* __restrict__ out)
{
    __shared__ float red[WSTOT];             // slice-reduced [cnt|sum|sq]
    __shared__ float means[BB][KK][CC];
    __shared__ float partial[BB];
    const int tid = threadIdx.x;

    // vectorized slice reduction: 528 float4, 16 independent loads each
    for (int i4 = tid; i4 < WSTOT / 4; i4 += 1024) {
        float4 t = {0.f, 0.f, 0.f, 0.f};
        #pragma unroll
        for (int s = 0; s < NSLICE; ++s) {
            float4 v = *(const float4*)(ws + (size_t)s * WSTOT + 4 * i4);
            t.x += v.x; t.y += v.y; t.z += v.z; t.w += v.w;
        }
        *(float4*)(red + 4 * i4) = t;
    }
    __syncthreads();

    const float* red_cnt = red;
    const float* red_sum = red + 64;
    const float* red_sq  = red + 64 + 1024;

    const int b = tid >> 6;       // one wave per batch (waves 0..3 active)
    const int lane = tid & 63;
    const bool active = tid < 256;

    const float DELTA_PULL = 0.5f;
    const float DELTA_PUSH = 1.5f;
    const float EPS = 1e-6f;

    unsigned long long bal = 0ull;
    float M = 0.f, pull_b = 0.f;

    if (active) {
        float cntk = 0.f;
        bool valid = false;
        float pull_k = 0.f;
        if (lane < KK) {
            int k = lane;
            cntk = red_cnt[b * KK + k];
            valid = cntk > 0.f;
            float safe = fmaxf_(cntk, 1.f);
            float acc_sq = 0.f, acc_ss = 0.f;
            #pragma unroll
            for (int c = 0; c < CC; ++c) {
                float sv = red_sum[(b * KK + k) * CC + c];
                means[b][k][c] = sv / safe;
                acc_sq += red_sq[(b * KK + k) * CC + c];
                acc_ss += sv * sv;
            }
            if (valid) pull_k = (acc_sq - acc_ss / cntk) / (cntk + EPS);
        }

        bal = __ballot(lane < KK && valid);
        M = (float)__popcll(bal);

        float ps = pull_k;
        #pragma unroll
        for (int d = 32; d >= 1; d >>= 1) ps += __shfl_xor(ps, d, 64);
        pull_b = ps / fmaxf_(M, 1.f);
    }

    __syncthreads();

    if (active) {
        float push = 0.f;
        for (int t = lane; t < KK * KK; t += 64) {
            int i = t >> 4, j = t & 15;
            if (i < j && ((bal >> i) & 1ull) && ((bal >> j) & 1ull)) {
                float d2 = 1e-12f;
                #pragma unroll
                for (int c = 0; c < CC; ++c) {
                    float df = means[b][i][c] - means[b][j][c];
                    d2 = fmaf(df, df, d2);
                }
                float dist = sqrtf(d2);
                float h = fmaxf_(DELTA_PUSH - dist, 0.f);
                push += h * h;
            }
        }
        #pragma unroll
        for (int d = 32; d >= 1; d >>= 1) push += __shfl_xor(push, d, 64);

        if (lane == 0) {
            float npairs = M * (M - 1.f) * 0.5f;
            float push_b = (M > 1.f) ? push / fmaxf_(npairs, 1.f) : 0.f;
            partial[b] = DELTA_PULL * pull_b + push_b;
        }
    }
    __syncthreads();
    if (tid == 0) {
        out[0] = (partial[0] + partial[1] + partial[2] + partial[3]) * 0.25f;
    }
}

extern "C" void kernel_launch(void* const* d_in, const int* in_sizes, int n_in,
                              void* d_out, int out_size, void* d_ws, size_t ws_size,
                              hipStream_t stream) {
    const float* emb = (const float*)d_in[0];
    const int* masks = (const int*)d_in[1];
    float* ws = (float*)d_ws;

    hipMemsetAsync(d_ws, 0, NSLICE * WSTOT * sizeof(float), stream);

    dim3 grid(BB * NTILES);
    disc_mfma_kernel<<<grid, THREADS, 0, stream>>>(emb, masks, ws);
    disc_finalize_kernel<<<1, 1024, 0, stream>>>(ws, (float*)d_out);
}